// Round 13
// baseline (404.837 us; speedup 1.0000x reference)
//
#include <hip/hip_runtime.h>
#include <math.h>

#define NVIEW 4
#define BATCH 4
#define NSEQ  256
#define CDIM  768
#define HEADS 12
#define HD    64

typedef __attribute__((ext_vector_type(8))) short   short8;
typedef __attribute__((ext_vector_type(8))) unsigned short ushort8;
typedef __attribute__((ext_vector_type(4))) float   float4v;

typedef const __attribute__((address_space(1))) void gas_t;
typedef       __attribute__((address_space(3))) void las_t;

__device__ __forceinline__ unsigned short f2b(float x)
{
    union { float f; unsigned u; } c; c.f = x;
    unsigned r = (c.u + 0x7FFFu + ((c.u >> 16) & 1u)) >> 16;
    return (unsigned short)r;
}

__device__ __forceinline__ unsigned pack2b(float a, float b)
{
    return (unsigned)f2b(a) | ((unsigned)f2b(b) << 16);
}

// ---------------------------------------------------------------------------
// LayerNorm row body
// ---------------------------------------------------------------------------
__device__ __forceinline__ void block_ln_row_b(const float* __restrict__ xrow,
                                               const float* __restrict__ g,
                                               const float* __restrict__ b,
                                               unsigned short* __restrict__ orow)
{
    const int t = threadIdx.x;
    float x0 = xrow[t], x1 = xrow[t + 256], x2 = xrow[t + 512];
    float s  = x0 + x1 + x2;
    float s2 = x0 * x0 + x1 * x1 + x2 * x2;
    #pragma unroll
    for (int off = 32; off > 0; off >>= 1) {
        s  += __shfl_down(s, off);
        s2 += __shfl_down(s2, off);
    }
    __shared__ float w1[4], w2[4];
    if ((t & 63) == 0) { w1[t >> 6] = s; w2[t >> 6] = s2; }
    __syncthreads();
    float S  = w1[0] + w1[1] + w1[2] + w1[3];
    float S2 = w2[0] + w2[1] + w2[2] + w2[3];
    float mean = S * (1.0f / 768.0f);
    float var  = S2 * (1.0f / 768.0f) - mean * mean;
    float inv  = rsqrtf(var + 1e-6f);
    orow[t]       = f2b((x0 - mean) * inv * g[t]       + b[t]);
    orow[t + 256] = f2b((x1 - mean) * inv * g[t + 256] + b[t + 256]);
    orow[t + 512] = f2b((x2 - mean) * inv * g[t + 512] + b[t + 512]);
}

// ---------------------------------------------------------------------------
// Fused prologue (long pole first). Conv is at its effective HBM ceiling once
// the harness's 256MB poison writeback (which drains during this kernel) is
// counted: (256+155)MB / 72us ~ 5.7 TB/s.
//   blocks [0, 4096):    ALL weights f32 -> bf16, grid-stride, wave-dense.
//   blocks [4096, 8192): LN1  X:[B,V,N,C] -> Xn bf16 [V,B,N,C]
//   blocks [8192, 8960): qh[v,d] = query . wq[v,d,:] + bq[v,d]
// Weight segments (elements): qkv [0,7077888) proj [..9437184)
//   fc1 [..18874368) fc2 [..28311552) mha_in [..35389440)
// ---------------------------------------------------------------------------
__global__ void prologue(const float* __restrict__ X, const float* __restrict__ n1g,
                         const float* __restrict__ n1b, unsigned short* __restrict__ Xn,
                         const float* __restrict__ query, const float* __restrict__ Win,
                         const float* __restrict__ Bin, float* __restrict__ QH,
                         const float* __restrict__ qkv, const float* __restrict__ proj,
                         const float* __restrict__ fc1, const float* __restrict__ fc2,
                         const float* __restrict__ mha, unsigned short* __restrict__ wdst)
{
    const int bid = blockIdx.x;
    const int t   = threadIdx.x;

    if (bid < 4096) {
        // ---- weight conversion, grid-stride, wave-dense loads ----
        const long NV = 35389440L;             // total f32 elements (mult of 2048)
        for (long base = (long)bid * 2048; base < NV; base += 4096L * 2048) {
            long i0 = base + t * 4;
            long i1 = i0 + 1024;
            const float* s0; long b0;
            if (i0 < 7077888L)       { s0 = qkv;  b0 = 0; }
            else if (i0 < 9437184L)  { s0 = proj; b0 = 7077888L; }
            else if (i0 < 18874368L) { s0 = fc1;  b0 = 9437184L; }
            else if (i0 < 28311552L) { s0 = fc2;  b0 = 18874368L; }
            else                     { s0 = mha;  b0 = 28311552L; }
            const float* s1; long b1;
            if (i1 < 7077888L)       { s1 = qkv;  b1 = 0; }
            else if (i1 < 9437184L)  { s1 = proj; b1 = 7077888L; }
            else if (i1 < 18874368L) { s1 = fc1;  b1 = 9437184L; }
            else if (i1 < 28311552L) { s1 = fc2;  b1 = 18874368L; }
            else                     { s1 = mha;  b1 = 28311552L; }
            float4 a = *(const float4*)(s0 + (i0 - b0));
            float4 b = *(const float4*)(s1 + (i1 - b1));
            unsigned long long pa = ((unsigned long long)pack2b(a.z, a.w) << 32) | pack2b(a.x, a.y);
            unsigned long long pb = ((unsigned long long)pack2b(b.z, b.w) << 32) | pack2b(b.x, b.y);
            *(unsigned long long*)(wdst + i0) = pa;
            *(unsigned long long*)(wdst + i1) = pb;
        }
        return;
    }

    if (bid < 8192) {
        // ---- LN1 ----
        int rid = bid - 4096;
        int n  = rid & 255;
        int bv = rid >> 8;
        int bb = bv >> 2, v = bv & 3;
        const float* xrow = X + (long)rid * CDIM;
        unsigned short* orow = Xn + ((long)(v * 4 + bb) * 256 + n) * CDIM;
        block_ln_row_b(xrow, n1g, n1b, orow);
        return;
    }

    // ---- qh: one wave per output row d ----
    {
        const int bi   = bid - 8192;           // 0..767
        const int v    = bi / 192;
        const int dblk = bi - v * 192;
        const int wave = t >> 6;
        const int lane = t & 63;
        const int d    = dblk * 4 + wave;

        __shared__ float qs[768];
        for (int idx = t; idx < 768; idx += 256) qs[idx] = query[idx];
        __syncthreads();

        const float* w = Win + ((long)v * 2304 + d) * 768;
        float acc = 0.f;
        #pragma unroll
        for (int k = 0; k < 3; ++k) {
            int c = k * 256 + lane * 4;
            float4 w4 = *(const float4*)(w + c);
            float4 q4 = *(const float4*)&qs[c];
            acc += w4.x * q4.x + w4.y * q4.y + w4.z * q4.z + w4.w * q4.w;
        }
        #pragma unroll
        for (int off = 32; off > 0; off >>= 1) acc += __shfl_down(acc, off);
        if (lane == 0)
            QH[v * 768 + d] = acc + Bin[(long)v * 2304 + d];
    }
}

// f32 in [V,B,N,C] -> bf16 out, per-view gamma/beta
__global__ void ln2_kernel(const float* __restrict__ Xin, const float* __restrict__ g,
                           const float* __restrict__ b, unsigned short* __restrict__ Out)
{
    int rid = blockIdx.x;
    int v = rid >> 10;
    const float* xrow = Xin + (long)rid * CDIM;
    block_ln_row_b(xrow, g + v * CDIM, b + v * CDIM, Out + (long)rid * CDIM);
}

// ---------------------------------------------------------------------------
// bf16 MFMA grouped GEMM: out[v] = A[v](M,K) * W[v]^T(N,K) + epilogue
// Single-buffered m97 structure (2 __syncthreads per K-tile), both operands
// staged bf16 via global_load_lds. BK templated:
//   TM=128, BK=64 : 32KB LDS, waves 2x2, 4x4 acc  (fc1: 768 blocks = exactly
//                   one full 3/CU generation)
//   TM=64,  BK=128: 48KB LDS, waves 1x4, 4x2 acc  (QKV, proj, fc2, KVH --
//                   more blocks + half the barrier drains per block)
// Row = CH chunks of 16B (CH=BK/8); logical chunk c at phys slot c^(row&7).
// XCD-aware block swizzle (all grids %8==0 -> bijective).
// EPI: 0=store bf16  1=+bias f32  2=+bias,gelu bf16  3=+bias,+resid(f32) bf16
//      4=(+bias)*2 f32
// ---------------------------------------------------------------------------
template <int EPI, int TM, int BK, typename OT>
__launch_bounds__(256, 3)
__global__ void gemm_bf16(const unsigned short* __restrict__ A,
                          const unsigned short* __restrict__ W,
                          const float* __restrict__ bias, const float* __restrict__ resid,
                          OT* __restrict__ out, int M, int N, int K,
                          long wStride, long wOff, int bStride, int bOff)
{
    // ---- XCD swizzle: XCD k gets a contiguous chunk of the linear grid ----
    const int nbx = gridDim.x, nby = gridDim.y;
    const int nwg = nbx * nby * (int)gridDim.z;
    const int orig = blockIdx.x + nbx * (blockIdx.y + nby * blockIdx.z);
    const int cpx = nwg >> 3;
    const int wid = (orig & 7) * cpx + (orig >> 3);
    const int bz  = wid / (nbx * nby);
    const int rr  = wid - bz * (nbx * nby);
    const int by  = rr / nbx;
    const int bx  = rr - by * nbx;

    const int v = bz;
    const unsigned short* Av = A + (long)v * M * K;
    const unsigned short* Wv = W + v * wStride + wOff;

    constexpr int CH  = BK / 8;            // 16B chunks per row
    constexpr int RPG = 512 / BK;          // rows per 1KB staging group (8 or 4)

    __shared__ unsigned short As[TM * BK];
    __shared__ unsigned short Bs[128 * BK];

    const int tid  = threadIdx.x;
    const int lane = tid & 63;
    const int wave = tid >> 6;
    const int l15  = lane & 15;
    const int quad = lane >> 4;
    const int row0 = by * TM, col0 = bx * 128;

    constexpr int MI = 4;
    constexpr int NI = (TM == 128) ? 4 : 2;
    const int mw = (TM == 128) ? (wave & 1) * 64 : 0;
    const int nw = (TM == 128) ? (wave >> 1) * 64 : wave * 32;

    float4v acc[MI][NI];
    #pragma unroll
    for (int i = 0; i < MI; ++i)
        #pragma unroll
        for (int j = 0; j < NI; ++j)
            acc[i][j] = (float4v){0.f, 0.f, 0.f, 0.f};

    const int lr = lane / CH;   // row within staging group
    const int pc = lane % CH;   // physical 16B slot

    for (int k0 = 0; k0 < K; k0 += BK) {
        __syncthreads();
        // stage A
        #pragma unroll
        for (int g = 0; g < TM / (RPG * 4); ++g) {
            int G = wave * (TM / (RPG * 4)) + g;
            int r = G * RPG + lr;
            int c = pc ^ (r & 7);
            const unsigned short* sa = Av + (long)(row0 + r) * K + k0 + c * 8;
            __builtin_amdgcn_global_load_lds((gas_t*)sa, (las_t*)&As[G * 512], 16, 0, 0);
        }
        // stage B
        #pragma unroll
        for (int g = 0; g < 128 / (RPG * 4); ++g) {
            int G = wave * (128 / (RPG * 4)) + g;
            int r = G * RPG + lr;
            int c = pc ^ (r & 7);
            const unsigned short* sw = Wv + (long)(col0 + r) * K + k0 + c * 8;
            __builtin_amdgcn_global_load_lds((gas_t*)sw, (las_t*)&Bs[G * 512], 16, 0, 0);
        }
        __syncthreads();

        #pragma unroll
        for (int ks = 0; ks < BK / 32; ++ks) {
            short8 af[MI], bfr[NI];
            #pragma unroll
            for (int mi = 0; mi < MI; ++mi) {
                int m = mw + mi * 16 + l15;
                int p = (ks * 4 + quad) ^ (m & 7);
                af[mi] = *(const short8*)&As[m * BK + p * 8];
            }
            #pragma unroll
            for (int ni = 0; ni < NI; ++ni) {
                int n = nw + ni * 16 + l15;
                int p = (ks * 4 + quad) ^ (n & 7);
                bfr[ni] = *(const short8*)&Bs[n * BK + p * 8];
            }
            #pragma unroll
            for (int mi = 0; mi < MI; ++mi)
                #pragma unroll
                for (int ni = 0; ni < NI; ++ni)
                    acc[mi][ni] = __builtin_amdgcn_mfma_f32_16x16x32_bf16(af[mi], bfr[ni], acc[mi][ni], 0, 0, 0);
        }
    }

    #pragma unroll
    for (int mi = 0; mi < MI; ++mi) {
        #pragma unroll
        for (int ni = 0; ni < NI; ++ni) {
            int rowb = row0 + mw + mi * 16 + quad * 4;
            int col  = col0 + nw + ni * 16 + l15;
            float bval = 0.f;
            if (EPI >= 1) bval = bias[v * bStride + bOff + col];
            #pragma unroll
            for (int r = 0; r < 4; ++r) {
                float x = acc[mi][ni][r] + bval;
                long off = (long)v * M * N + (long)(rowb + r) * N + col;
                if constexpr (EPI == 2) {
                    x = 0.5f * x * (1.0f + erff(x * 0.70710678118654752f));
                } else if constexpr (EPI == 3) {
                    x += resid[off];
                } else if constexpr (EPI == 4) {
                    x *= 2.0f;
                }
                if constexpr (sizeof(OT) == 2) ((unsigned short*)out)[off] = f2b(x);
                else                           ((float*)out)[off] = x;
            }
        }
    }
}

// ---------------------------------------------------------------------------
// Fused MFMA fusion-attention (best measured config).
// grid (qt=4, b*h=48, i=4); block 256 = 4 waves; each wave owns 16 query rows.
// Swapped-operand scheme:
//   QK: mfma(kf, qf) -> S^T tile: lane = query (l15), regs = 4 contiguous keys.
//   PV: mfma(vf, pf) -> O^T tile: lane = query, regs = 4 contiguous d.
// LDS: KVu is Ks[128x64] during QK, Vt[64][136] during PV (union, 44032 B
// total -> 3 blocks/CU). V rows prefetched to regs one half ahead.
// ---------------------------------------------------------------------------
__launch_bounds__(256, 3)
__global__ void fusion_attn_mfma(const unsigned short* __restrict__ QKV,
                                 unsigned short* __restrict__ ctx)
{
    const int qt = blockIdx.x;
    const int b  = blockIdx.y / HEADS;
    const int h  = blockIdx.y % HEADS;
    const int i  = blockIdx.z;
    const int tid  = threadIdx.x;
    const int lane = tid & 63;
    const int wave = tid >> 6;
    const int l15  = lane & 15;
    const int quad = lane >> 4;

    __shared__ unsigned short Qs[64 * 72];     //  9216 B, wave-private rows
    __shared__ unsigned short KVu[64 * 136];   // 17408 B: Ks (QK) U Vt (PV)
    __shared__ unsigned short Ps[64 * 136];    // 17408 B

    {
        int r = tid >> 2, p16 = (tid & 3) * 16;
        const unsigned short* src = QKV + ((long)((i * 4 + b) * 256 + qt * 64 + r)) * 2304 + h * 64 + p16;
        *(ushort8*)(&Qs[r * 72 + p16])     = *(const ushort8*)(src);
        *(ushort8*)(&Qs[r * 72 + p16 + 8]) = *(const ushort8*)(src + 8);
    }

    const int kg = tid & 31;   // V prefetch: key group of 4 rows
    const int dc = tid >> 5;   // V prefetch: d-chunk (8 d-values)

    float4v acc_o[4];
    #pragma unroll
    for (int e = 0; e < 4; ++e) acc_o[e] = (float4v){0.f, 0.f, 0.f, 0.f};

    for (int j = 0; j < 4; ++j) {
        const unsigned short* Kb = QKV + ((long)((j * 4 + b) * 256)) * 2304 + 768 + h * 64;
        const unsigned short* Vb = Kb + 768;

        float4v sacc[16];
        #pragma unroll
        for (int t = 0; t < 16; ++t) sacc[t] = (float4v){0.f, 0.f, 0.f, 0.f};

        ushort8 vv0[4], vv1[4];

        // ---------------- QK half 0 ----------------
        __syncthreads();
        #pragma unroll
        for (int g = 0; g < 4; ++g) {
            int R = wave * 32 + g * 8;
            int r = R + (lane >> 3);
            int p = lane & 7;
            int c = (p - (r & 7)) & 7;
            const unsigned short* src = Kb + (long)(r) * 2304 + c * 8;
            __builtin_amdgcn_global_load_lds((gas_t*)src, (las_t*)&KVu[R * 64], 16, 0, 0);
        }
        __syncthreads();
        __builtin_amdgcn_s_setprio(1);
        #pragma unroll
        for (int ks = 0; ks < 2; ++ks) {
            int lcq = ks * 4 + quad;
            short8 qf = *(const short8*)&Qs[(wave * 16 + l15) * 72 + lcq * 8];
            #pragma unroll
            for (int nn = 0; nn < 8; ++nn) {
                int n = nn * 16 + l15;
                int p = (lcq + (n & 7)) & 7;
                short8 kf = *(const short8*)&KVu[n * 64 + p * 8];
                sacc[nn] = __builtin_amdgcn_mfma_f32_16x16x32_bf16(kf, qf, sacc[nn], 0, 0, 0);
            }
        }
        __builtin_amdgcn_s_setprio(0);

        // ---------------- QK half 1 ----------------
        __syncthreads();
        #pragma unroll
        for (int g = 0; g < 4; ++g) {
            int R = wave * 32 + g * 8;
            int r = R + (lane >> 3);
            int p = lane & 7;
            int c = (p - (r & 7)) & 7;
            const unsigned short* src = Kb + (long)(128 + r) * 2304 + c * 8;
            __builtin_amdgcn_global_load_lds((gas_t*)src, (las_t*)&KVu[R * 64], 16, 0, 0);
        }
        __builtin_amdgcn_sched_barrier(0);
        #pragma unroll
        for (int q = 0; q < 4; ++q)                // prefetch V half 0
            vv0[q] = *(const ushort8*)(Vb + (long)(kg * 4 + q) * 2304 + dc * 8);
        asm volatile("s_waitcnt vmcnt(4) lgkmcnt(0)" ::: "memory");
        __builtin_amdgcn_s_barrier();
        __builtin_amdgcn_sched_barrier(0);
        __builtin_amdgcn_s_setprio(1);
        #pragma unroll
        for (int ks = 0; ks < 2; ++ks) {
            int lcq = ks * 4 + quad;
            short8 qf = *(const short8*)&Qs[(wave * 16 + l15) * 72 + lcq * 8];
            #pragma unroll
            for (int nn = 0; nn < 8; ++nn) {
                int n = nn * 16 + l15;
                int p = (lcq + (n & 7)) & 7;
                short8 kf = *(const short8*)&KVu[n * 64 + p * 8];
                sacc[8 + nn] = __builtin_amdgcn_mfma_f32_16x16x32_bf16(kf, qf, sacc[8 + nn], 0, 0, 0);
            }
        }
        __builtin_amdgcn_s_setprio(0);

        // ---------------- softmax (register, per-query = per-lane) ----------
        float m = -1e30f;
        #pragma unroll
        for (int t = 0; t < 16; ++t)
            #pragma unroll
            for (int r = 0; r < 4; ++r) {
                sacc[t][r] *= 0.125f;
                m = fmaxf(m, sacc[t][r]);
            }
        m = fmaxf(m, __shfl_xor(m, 16));
        m = fmaxf(m, __shfl_xor(m, 32));
        float lsum = 0.f;
        #pragma unroll
        for (int t = 0; t < 16; ++t)
            #pragma unroll
            for (int r = 0; r < 4; ++r) {
                float e = __expf(sacc[t][r] - m);
                sacc[t][r] = e;
                lsum += e;
            }
        lsum += __shfl_xor(lsum, 16);
        lsum += __shfl_xor(lsum, 32);
        float invl = 1.0f / lsum;

        float4v pv[4];
        #pragma unroll
        for (int e = 0; e < 4; ++e) pv[e] = (float4v){0.f, 0.f, 0.f, 0.f};

        // ---------------- PV half 0 ----------------
        __syncthreads();
        #pragma unroll
        for (int nn = 0; nn < 8; ++nn) {
            unsigned lo = pack2b(sacc[nn][0], sacc[nn][1]);
            unsigned hi = pack2b(sacc[nn][2], sacc[nn][3]);
            *(unsigned long long*)&Ps[(wave * 16 + l15) * 136 + nn * 16 + quad * 4] =
                ((unsigned long long)hi << 32) | lo;
        }
        #pragma unroll
        for (int jj = 0; jj < 8; ++jj) {
            unsigned lo = (unsigned)vv0[0][jj] | ((unsigned)vv0[1][jj] << 16);
            unsigned hi = (unsigned)vv0[2][jj] | ((unsigned)vv0[3][jj] << 16);
            *(unsigned long long*)&KVu[(dc * 8 + jj) * 136 + kg * 4] =
                ((unsigned long long)hi << 32) | lo;
        }
        #pragma unroll
        for (int q = 0; q < 4; ++q)                // prefetch V half 1
            vv1[q] = *(const ushort8*)(Vb + (long)(128 + kg * 4 + q) * 2304 + dc * 8);
        asm volatile("s_waitcnt lgkmcnt(0)" ::: "memory");
        __builtin_amdgcn_s_barrier();
        __builtin_amdgcn_sched_barrier(0);
        __builtin_amdgcn_s_setprio(1);
        #pragma unroll
        for (int ks = 0; ks < 4; ++ks) {
            int lc = ks * 4 + quad;
            short8 pf = *(const short8*)&Ps[(wave * 16 + l15) * 136 + lc * 8];
            #pragma unroll
            for (int et = 0; et < 4; ++et) {
                short8 vf = *(const short8*)&KVu[(et * 16 + l15) * 136 + lc * 8];
                pv[et] = __builtin_amdgcn_mfma_f32_16x16x32_bf16(vf, pf, pv[et], 0, 0, 0);
            }
        }
        __builtin_amdgcn_s_setprio(0);

        // ---------------- PV half 1 ----------------
        __syncthreads();
        #pragma unroll
        for (int nn = 0; nn < 8; ++nn) {
            unsigned lo = pack2b(sacc[8 + nn][0], sacc[8 + nn][1]);
            unsigned hi = pack2b(sacc[8 + nn][2], sacc[8 + nn][3]);
            *(unsigned long long*)&Ps[(wave * 16 + l15) * 136 + nn * 16 + quad * 4] =
                ((unsigned long long)hi << 32) | lo;
        }
        #pragma unroll
        for (int jj = 0; jj < 8; ++jj) {
            unsigned lo = (unsigned)vv1[0][jj] | ((unsigned)vv1[1][jj] << 16);
            unsigned hi = (unsigned)vv1[2][jj] | ((unsigned)vv1[3][jj] << 16);
            *(unsigned long long*)&KVu[(dc * 8 + jj) * 136 + kg * 4] =
                ((unsigned long long)hi << 32) | lo;
        }
        __syncthreads();
        __builtin_amdgcn_s_setprio(1);
        #pragma unroll
        for (int ks = 0; ks < 4; ++ks) {
            int lc = ks * 4 + quad;
            short8 pf = *(const short8*)&Ps[(wave * 16 + l15) * 136 + lc * 8];
            #pragma unroll
            for (int et = 0; et < 4; ++et) {
                short8 vf = *(const short8*)&KVu[(et * 16 + l15) * 136 + lc * 8];
                pv[et] = __builtin_amdgcn_mfma_f32_16x16x32_bf16(vf, pf, pv[et], 0, 0, 0);
            }
        }
        __builtin_amdgcn_s_setprio(0);

        #pragma unroll
        for (int et = 0; et < 4; ++et)
            #pragma unroll
            for (int r = 0; r < 4; ++r)
                acc_o[et][r] += pv[et][r] * invl;
    }

    #pragma unroll
    for (int et = 0; et < 4; ++et) {
        unsigned lo = pack2b(acc_o[et][0] * 0.25f, acc_o[et][1] * 0.25f);
        unsigned hi = pack2b(acc_o[et][2] * 0.25f, acc_o[et][3] * 0.25f);
        long row = (long)((i * 4 + b) * 256 + qt * 64 + wave * 16 + l15);
        int  col = h * 64 + et * 16 + quad * 4;
        *(unsigned long long*)&ctx[row * 768 + col] = ((unsigned long long)hi << 32) | lo;
    }
}

// ---------------------------------------------------------------------------
// Learnable-query cross attention (f32). KVH [V,B,N,1536]: k then v.
// ---------------------------------------------------------------------------
__launch_bounds__(256, 2)
__global__ void cross_attn(const float* __restrict__ KVH, const float* __restrict__ QH,
                           float* __restrict__ C2)
{
    const int h = blockIdx.x, b = blockIdx.y, v = blockIdx.z;
    const int t = threadIdx.x;
    __shared__ float qv[64];
    __shared__ float p[256];
    __shared__ float part[4][64];
    __shared__ float wred[4], wred2[4];

    if (t < 64) qv[t] = QH[(v * 12 + h) * 64 + t];
    __syncthreads();

    const float* krow = KVH + ((long)((v * 4 + b) * 256 + t)) * 1536 + h * 64;
    float s = 0.f;
    #pragma unroll
    for (int e = 0; e < 64; e += 4) {
        float4 k4 = *(const float4*)(krow + e);
        s += qv[e] * k4.x + qv[e + 1] * k4.y + qv[e + 2] * k4.z + qv[e + 3] * k4.w;
    }
    s *= 0.125f;
    float m4 = s;
    #pragma unroll
    for (int off = 32; off > 0; off >>= 1) m4 = fmaxf(m4, __shfl_down(m4, off));
    if ((t & 63) == 0) wred[t >> 6] = m4;
    __syncthreads();
    float rmax = fmaxf(fmaxf(wred[0], wred[1]), fmaxf(wred[2], wred[3]));
    float ev = __expf(s - rmax);
    p[t] = ev;
    float s4 = ev;
    #pragma unroll
    for (int off = 32; off > 0; off >>= 1) s4 += __shfl_down(s4, off);
    if ((t & 63) == 0) wred2[t >> 6] = s4;
    __syncthreads();
    float inv = 1.0f / (wred2[0] + wred2[1] + wred2[2] + wred2[3]);

    const int e = t & 63, ch = t >> 6;
    const float* vbase = KVH + ((long)((v * 4 + b) * 256)) * 1536 + 768 + h * 64 + e;
    float accv = 0.f;
    for (int m = ch * 64; m < ch * 64 + 64; ++m)
        accv += p[m] * vbase[(long)m * 1536];
    part[ch][e] = accv;
    __syncthreads();
    if (t < 64)
        C2[(v * 4 + b) * 768 + h * 64 + t] =
            (part[0][t] + part[1][t] + part[2][t] + part[3][t]) * inv;
}

// ---------------------------------------------------------------------------
// out stage 1: one wave per output row d; 768 blocks x 4 waves.
// ---------------------------------------------------------------------------
__launch_bounds__(256, 4)
__global__ void out_matvec(const float* __restrict__ C2, const float* __restrict__ Wout,
                           const float* __restrict__ Bout, float* __restrict__ obc)
{
    const int bi   = blockIdx.x;
    const int v    = bi / 192;
    const int dblk = bi - v * 192;
    const int t    = threadIdx.x;
    const int wave = t >> 6;
    const int lane = t & 63;
    const int d    = dblk * 4 + wave;

    __shared__ float c2s[3072];
    #pragma unroll
    for (int idx = 0; idx < 3072; idx += 256) c2s[idx + t] = C2[v * 3072 + idx + t];
    __syncthreads();

    const float* w = Wout + ((long)v * 768 + d) * 768;
    float acc0 = 0.f, acc1 = 0.f, acc2 = 0.f, acc3 = 0.f;
    #pragma unroll
    for (int k = 0; k < 3; ++k) {
        int c = k * 256 + lane * 4;
        float4 w4 = *(const float4*)(w + c);
        float4 a0 = *(const float4*)&c2s[c];
        float4 a1 = *(const float4*)&c2s[768 + c];
        float4 a2 = *(const float4*)&c2s[1536 + c];
        float4 a3 = *(const float4*)&c2s[2304 + c];
        acc0 += w4.x * a0.x + w4.y * a0.y + w4.z * a0.z + w4.w * a0.w;
        acc1 += w4.x * a1.x + w4.y * a1.y + w4.z * a1.z + w4.w * a1.w;
        acc2 += w4.x * a2.x + w4.y * a2.y + w4.z * a2.z + w4.w * a2.w;
        acc3 += w4.x * a3.x + w4.y * a3.y + w4.z * a3.z + w4.w * a3.w;
    }
    #pragma unroll
    for (int off = 32; off > 0; off >>= 1) {
        acc0 += __shfl_down(acc0, off);
        acc1 += __shfl_down(acc1, off);
        acc2 += __shfl_down(acc2, off);
        acc3 += __shfl_down(acc3, off);
    }
    if (lane == 0) {
        float bb = Bout[v * 768 + d];
        obc[0 * 3072 + v * 768 + d] = acc0 + bb;
        obc[1 * 3072 + v * 768 + d] = acc1 + bb;
        obc[2 * 3072 + v * 768 + d] = acc2 + bb;
        obc[3 * 3072 + v * 768 + d] = acc3 + bb;
    }
}

// ---------------------------------------------------------------------------
// out stage 2: broadcast over N
// ---------------------------------------------------------------------------
__launch_bounds__(256, 4)
__global__ void out_bcast(const float* __restrict__ obc, float* __restrict__ out)
{
    const int b  = blockIdx.x >> 6;
    const int n0 = (blockIdx.x & 63) * 4;
    const int t  = threadIdx.x;
    const float4* src = (const float4*)(obc + (long)b * 3072);
    float4 v0 = src[t], v1 = src[t + 256], v2 = src[t + 512];
    float4* dst = (float4*)(out + ((long)(b * 256 + n0)) * 3072);
    #pragma unroll
    for (int r = 0; r < 4; ++r) {
        dst[r * 768 + t]       = v0;
        dst[r * 768 + t + 256] = v1;
        dst[r * 768 + t + 512] = v2;
    }
}

// ---------------------------------------------------------------------------
extern "C" void kernel_launch(void* const* d_in, const int* in_sizes, int n_in,
                              void* d_out, int out_size, void* d_ws, size_t ws_size,
                              hipStream_t stream)
{
    const float* X        = (const float*)d_in[0];
    const float* n1g      = (const float*)d_in[1];
    const float* n1b      = (const float*)d_in[2];
    const float* qkv_w    = (const float*)d_in[3];
    const float* proj_w   = (const float*)d_in[4];
    const float* proj_b   = (const float*)d_in[5];
    const float* n2g      = (const float*)d_in[6];
    const float* n2b      = (const float*)d_in[7];
    const float* fc1_w    = (const float*)d_in[8];
    const float* fc1_b    = (const float*)d_in[9];
    const float* fc2_w    = (const float*)d_in[10];
    const float* fc2_b    = (const float*)d_in[11];
    const float* query    = (const float*)d_in[12];
    const float* mha_in_w = (const float*)d_in[13];
    const float* mha_in_b = (const float*)d_in[14];
    const float* mha_out_w= (const float*)d_in[15];
    const float* mha_out_b= (const float*)d_in[16];
    float* out = (float*)d_out;

    // ws is 256 MiB -> all bf16 weights coexist. Element offsets in wbuf:
    //   qkv 0 | proj 7077888 | fc1 9437184 | fc2 18874368 | mha_in 28311552
    char* wsb = (char*)d_ws;
    unsigned short* wbuf = (unsigned short*)wsb;                    // 70,778,880 B
    unsigned short* rgA  = (unsigned short*)(wsb + 70778880);       //  6,291,456 B (Xn -> ctx -> h -> x2)
    char*           rgB  = wsb + 77070336;                          // 25,165,824 B (QKV -> h1 -> KVH)
    float*          xbuf = (float*)(wsb + 102236160);               // 12,582,912 B (x residual, f32)
    float*          qh   = (float*)(wsb + 114819072);               // 12,288 B
    float*          c2   = (float*)(wsb + 114831360);               // 49,152 B
    float*          obc  = (float*)(wsb + 114880512);               // 49,152 B

    unsigned short* QKV = (unsigned short*)rgB;
    unsigned short* H1  = (unsigned short*)rgB;
    float*          KVH = (float*)rgB;

    // 1. fused prologue: conv (4096, long-pole-first) + LN1 (4096) + qh (768)
    prologue<<<8960, 256, 0, stream>>>(X, n1g, n1b, rgA,
                                       query, mha_in_w, mha_in_b, qh,
                                       qkv_w, proj_w, fc1_w, fc2_w, mha_in_w, wbuf);
    // 2. QKV = Xn @ qkv_w^T  [V,1024,2304] bf16   (TM=64/BK=128; 1152 blocks)
    gemm_bf16<0, 64, 128, unsigned short><<<dim3(18, 16, 4), 256, 0, stream>>>(
        rgA, wbuf, nullptr, nullptr, QKV, 1024, 2304, 768, 2304L * 768, 0, 0, 0);
    // 3. fusion attention -> ctx_mean bf16 [V,1024,768]
    fusion_attn_mfma<<<dim3(4, 48, 4), 256, 0, stream>>>(QKV, rgA);
    // 4. x = 2*(ctx @ proj_w^T + proj_b)  f32    (TM=64/BK=128; 384 blocks)
    gemm_bf16<4, 64, 128, float><<<dim3(6, 16, 4), 256, 0, stream>>>(
        rgA, wbuf + 7077888, proj_b, nullptr, xbuf, 1024, 768, 768, 768L * 768, 0, 768, 0);
    // 5. h = LN2(x) bf16
    ln2_kernel<<<4096, 256, 0, stream>>>(xbuf, n2g, n2b, rgA);
    // 6. h1 = gelu(h @ fc1_w^T + fc1_b) bf16 [V,1024,3072]  (TM=128/BK=64; 768 blocks)
    gemm_bf16<2, 128, 64, unsigned short><<<dim3(24, 8, 4), 256, 0, stream>>>(
        rgA, wbuf + 9437184, fc1_b, nullptr, H1, 1024, 3072, 768, 3072L * 768, 0, 3072, 0);
    // 7. x2 = x + (h1 @ fc2_w^T + fc2_b) bf16   (TM=64/BK=128; 384 blocks)
    gemm_bf16<3, 64, 128, unsigned short><<<dim3(6, 16, 4), 256, 0, stream>>>(
        H1, wbuf + 18874368, fc2_b, xbuf, rgA, 1024, 768, 3072, 768L * 3072, 0, 768, 0);
    // 8. KVH = x2 @ [wk;wv]^T + [bk;bv]  f32 [V,1024,1536]  (TM=64/BK=128; 768 blocks)
    gemm_bf16<1, 64, 128, float><<<dim3(12, 16, 4), 256, 0, stream>>>(
        rgA, wbuf + 28311552, mha_in_b, nullptr, KVH, 1024, 1536, 768, 2304L * 768, 768L * 768, 2304, 768);
    // 9. small tail
    cross_attn<<<dim3(12, 4, 4), 256, 0, stream>>>(KVH, qh, c2);
    out_matvec<<<768, 256, 0, stream>>>(c2, mha_out_w, mha_out_b, obc);
    out_bcast<<<256, 256, 0, stream>>>(obc, out);
}

// Round 14
// 392.783 us; speedup vs baseline: 1.0307x; 1.0307x over previous
//
#include <hip/hip_runtime.h>
#include <math.h>

#define NVIEW 4
#define BATCH 4
#define NSEQ  256
#define CDIM  768
#define HEADS 12
#define HD    64

typedef __attribute__((ext_vector_type(8))) short   short8;
typedef __attribute__((ext_vector_type(8))) unsigned short ushort8;
typedef __attribute__((ext_vector_type(4))) float   float4v;

typedef const __attribute__((address_space(1))) void gas_t;
typedef       __attribute__((address_space(3))) void las_t;

__device__ __forceinline__ unsigned short f2b(float x)
{
    union { float f; unsigned u; } c; c.f = x;
    unsigned r = (c.u + 0x7FFFu + ((c.u >> 16) & 1u)) >> 16;
    return (unsigned short)r;
}

__device__ __forceinline__ unsigned pack2b(float a, float b)
{
    return (unsigned)f2b(a) | ((unsigned)f2b(b) << 16);
}

// ---------------------------------------------------------------------------
// LayerNorm row body (callable from fused prologue)
// ---------------------------------------------------------------------------
__device__ __forceinline__ void block_ln_row_b(const float* __restrict__ xrow,
                                               const float* __restrict__ g,
                                               const float* __restrict__ b,
                                               unsigned short* __restrict__ orow)
{
    const int t = threadIdx.x;
    float x0 = xrow[t], x1 = xrow[t + 256], x2 = xrow[t + 512];
    float s  = x0 + x1 + x2;
    float s2 = x0 * x0 + x1 * x1 + x2 * x2;
    #pragma unroll
    for (int off = 32; off > 0; off >>= 1) {
        s  += __shfl_down(s, off);
        s2 += __shfl_down(s2, off);
    }
    __shared__ float w1[4], w2[4];
    if ((t & 63) == 0) { w1[t >> 6] = s; w2[t >> 6] = s2; }
    __syncthreads();
    float S  = w1[0] + w1[1] + w1[2] + w1[3];
    float S2 = w2[0] + w2[1] + w2[2] + w2[3];
    float mean = S * (1.0f / 768.0f);
    float var  = S2 * (1.0f / 768.0f) - mean * mean;
    float inv  = rsqrtf(var + 1e-6f);
    orow[t]       = f2b((x0 - mean) * inv * g[t]       + b[t]);
    orow[t + 256] = f2b((x1 - mean) * inv * g[t + 256] + b[t + 256]);
    orow[t + 512] = f2b((x2 - mean) * inv * g[t + 512] + b[t + 512]);
}

// ---------------------------------------------------------------------------
// Fused prologue: three independent jobs in one launch, LONG POLE FIRST so
// the streaming weight-conversion starts immediately and LN1/qh backfill.
//   blocks [0, 4096):    ALL weights f32 -> bf16, grid-stride (4.2 chunks/thr)
//   blocks [4096, 8192): LN1  X:[B,V,N,C] -> Xn bf16 [V,B,N,C]
//   blocks [8192, 8960): qh[v,d] = query . wq[v,d,:] + bq[v,d]
// The conv is at its effective HBM ceiling once the harness's 256MB poison
// writeback (draining during this kernel) is counted: ~(256+155)MB/70us
// ~ 5.8 TB/s.
// Weight segment boundaries (elements, all %8==0):
//   qkv [0,7077888) proj [.. 9437184) fc1 [.. 18874368) fc2 [.. 28311552)
//   mha_in [.. 35389440)
// ---------------------------------------------------------------------------
__global__ void prologue(const float* __restrict__ X, const float* __restrict__ n1g,
                         const float* __restrict__ n1b, unsigned short* __restrict__ Xn,
                         const float* __restrict__ query, const float* __restrict__ Win,
                         const float* __restrict__ Bin, float* __restrict__ QH,
                         const float* __restrict__ qkv, const float* __restrict__ proj,
                         const float* __restrict__ fc1, const float* __restrict__ fc2,
                         const float* __restrict__ mha, unsigned short* __restrict__ wdst)
{
    const int bid = blockIdx.x;
    const int t   = threadIdx.x;

    if (bid < 4096) {
        // ---- weight conversion, grid-stride (long pole -- dispatched first) ----
        const long NV8 = 4423680L;             // 35389440 / 8
        long vi = (long)bid * 256 + t;
        #pragma unroll 2
        for (; vi < NV8; vi += 4096L * 256) {
            long idx = vi * 8;
            const float* s;
            long base;
            if (idx < 7077888L)       { s = qkv;  base = 0; }
            else if (idx < 9437184L)  { s = proj; base = 7077888L; }
            else if (idx < 18874368L) { s = fc1;  base = 9437184L; }
            else if (idx < 28311552L) { s = fc2;  base = 18874368L; }
            else                      { s = mha;  base = 28311552L; }
            const float* sp = s + (idx - base);
            float4 a = *(const float4*)sp;
            float4 b = *(const float4*)(sp + 4);
            ushort8 o;
            o[0] = f2b(a.x); o[1] = f2b(a.y); o[2] = f2b(a.z); o[3] = f2b(a.w);
            o[4] = f2b(b.x); o[5] = f2b(b.y); o[6] = f2b(b.z); o[7] = f2b(b.w);
            *(ushort8*)(wdst + idx) = o;
        }
        return;
    }

    if (bid < 8192) {
        // ---- LN1 ----
        int rid = bid - 4096;
        int n  = rid & 255;
        int bv = rid >> 8;
        int bb = bv >> 2, v = bv & 3;
        const float* xrow = X + (long)rid * CDIM;
        unsigned short* orow = Xn + ((long)(v * 4 + bb) * 256 + n) * CDIM;
        block_ln_row_b(xrow, n1g, n1b, orow);
        return;
    }

    // ---- qh: one wave per output row d ----
    {
        const int bi   = bid - 8192;           // 0..767
        const int v    = bi / 192;
        const int dblk = bi - v * 192;
        const int wave = t >> 6;
        const int lane = t & 63;
        const int d    = dblk * 4 + wave;

        __shared__ float qs[768];
        for (int idx = t; idx < 768; idx += 256) qs[idx] = query[idx];
        __syncthreads();

        const float* w = Win + ((long)v * 2304 + d) * 768;
        float acc = 0.f;
        #pragma unroll
        for (int k = 0; k < 3; ++k) {
            int c = k * 256 + lane * 4;
            float4 w4 = *(const float4*)(w + c);
            float4 q4 = *(const float4*)&qs[c];
            acc += w4.x * q4.x + w4.y * q4.y + w4.z * q4.z + w4.w * q4.w;
        }
        #pragma unroll
        for (int off = 32; off > 0; off >>= 1) acc += __shfl_down(acc, off);
        if (lane == 0)
            QH[v * 768 + d] = acc + Bin[(long)v * 2304 + d];
    }
}

// f32 in [V,B,N,C] -> bf16 out, per-view gamma/beta
__global__ void ln2_kernel(const float* __restrict__ Xin, const float* __restrict__ g,
                           const float* __restrict__ b, unsigned short* __restrict__ Out)
{
    int rid = blockIdx.x;
    int v = rid >> 10;
    const float* xrow = Xin + (long)rid * CDIM;
    block_ln_row_b(xrow, g + v * CDIM, b + v * CDIM, Out + (long)rid * CDIM);
}

// ---------------------------------------------------------------------------
// bf16 MFMA grouped GEMM: out[v] = A[v](M,K) * W[v]^T(N,K) + epilogue
// Single-buffered m97 structure (2 __syncthreads per K-tile), both operands
// staged bf16 via global_load_lds. BK templated:
//   TM=128, BK=64 : 32KB LDS, waves 2x2, 4x4 acc  (QKV, fc1)
//   TM=64,  BK=128: 48KB LDS, waves 1x4, 4x2 acc  (proj, fc2, KVH)
// Row = CH chunks of 16B (CH=BK/8); logical chunk c at phys slot c^(row&7).
// XCD-aware block swizzle (all grids %8==0 -> bijective).
// EPI: 0=store bf16  1=+bias f32  2=+bias,gelu bf16  3=+bias,+resid(f32) bf16
//      4=(+bias)*2 f32
// ---------------------------------------------------------------------------
template <int EPI, int TM, int BK, typename OT>
__launch_bounds__(256, 3)
__global__ void gemm_bf16(const unsigned short* __restrict__ A,
                          const unsigned short* __restrict__ W,
                          const float* __restrict__ bias, const float* __restrict__ resid,
                          OT* __restrict__ out, int M, int N, int K,
                          long wStride, long wOff, int bStride, int bOff)
{
    // ---- XCD swizzle: XCD k gets a contiguous chunk of the linear grid ----
    const int nbx = gridDim.x, nby = gridDim.y;
    const int nwg = nbx * nby * (int)gridDim.z;
    const int orig = blockIdx.x + nbx * (blockIdx.y + nby * blockIdx.z);
    const int cpx = nwg >> 3;
    const int wid = (orig & 7) * cpx + (orig >> 3);
    const int bz  = wid / (nbx * nby);
    const int rr  = wid - bz * (nbx * nby);
    const int by  = rr / nbx;
    const int bx  = rr - by * nbx;

    const int v = bz;
    const unsigned short* Av = A + (long)v * M * K;
    const unsigned short* Wv = W + v * wStride + wOff;

    constexpr int CH  = BK / 8;            // 16B chunks per row
    constexpr int RPG = 512 / BK;          // rows per 1KB staging group (8 or 4)

    __shared__ unsigned short As[TM * BK];
    __shared__ unsigned short Bs[128 * BK];

    const int tid  = threadIdx.x;
    const int lane = tid & 63;
    const int wave = tid >> 6;
    const int l15  = lane & 15;
    const int quad = lane >> 4;
    const int row0 = by * TM, col0 = bx * 128;

    constexpr int MI = 4;
    constexpr int NI = (TM == 128) ? 4 : 2;
    const int mw = (TM == 128) ? (wave & 1) * 64 : 0;
    const int nw = (TM == 128) ? (wave >> 1) * 64 : wave * 32;

    float4v acc[MI][NI];
    #pragma unroll
    for (int i = 0; i < MI; ++i)
        #pragma unroll
        for (int j = 0; j < NI; ++j)
            acc[i][j] = (float4v){0.f, 0.f, 0.f, 0.f};

    const int lr = lane / CH;   // row within staging group
    const int pc = lane % CH;   // physical 16B slot

    for (int k0 = 0; k0 < K; k0 += BK) {
        __syncthreads();
        // stage A
        #pragma unroll
        for (int g = 0; g < TM / (RPG * 4); ++g) {
            int G = wave * (TM / (RPG * 4)) + g;
            int r = G * RPG + lr;
            int c = pc ^ (r & 7);
            const unsigned short* sa = Av + (long)(row0 + r) * K + k0 + c * 8;
            __builtin_amdgcn_global_load_lds((gas_t*)sa, (las_t*)&As[G * 512], 16, 0, 0);
        }
        // stage B
        #pragma unroll
        for (int g = 0; g < 128 / (RPG * 4); ++g) {
            int G = wave * (128 / (RPG * 4)) + g;
            int r = G * RPG + lr;
            int c = pc ^ (r & 7);
            const unsigned short* sw = Wv + (long)(col0 + r) * K + k0 + c * 8;
            __builtin_amdgcn_global_load_lds((gas_t*)sw, (las_t*)&Bs[G * 512], 16, 0, 0);
        }
        __syncthreads();

        #pragma unroll
        for (int ks = 0; ks < BK / 32; ++ks) {
            short8 af[MI], bfr[NI];
            #pragma unroll
            for (int mi = 0; mi < MI; ++mi) {
                int m = mw + mi * 16 + l15;
                int p = (ks * 4 + quad) ^ (m & 7);
                af[mi] = *(const short8*)&As[m * BK + p * 8];
            }
            #pragma unroll
            for (int ni = 0; ni < NI; ++ni) {
                int n = nw + ni * 16 + l15;
                int p = (ks * 4 + quad) ^ (n & 7);
                bfr[ni] = *(const short8*)&Bs[n * BK + p * 8];
            }
            #pragma unroll
            for (int mi = 0; mi < MI; ++mi)
                #pragma unroll
                for (int ni = 0; ni < NI; ++ni)
                    acc[mi][ni] = __builtin_amdgcn_mfma_f32_16x16x32_bf16(af[mi], bfr[ni], acc[mi][ni], 0, 0, 0);
        }
    }

    #pragma unroll
    for (int mi = 0; mi < MI; ++mi) {
        #pragma unroll
        for (int ni = 0; ni < NI; ++ni) {
            int rowb = row0 + mw + mi * 16 + quad * 4;
            int col  = col0 + nw + ni * 16 + l15;
            float bval = 0.f;
            if (EPI >= 1) bval = bias[v * bStride + bOff + col];
            #pragma unroll
            for (int r = 0; r < 4; ++r) {
                float x = acc[mi][ni][r] + bval;
                long off = (long)v * M * N + (long)(rowb + r) * N + col;
                if constexpr (EPI == 2) {
                    x = 0.5f * x * (1.0f + erff(x * 0.70710678118654752f));
                } else if constexpr (EPI == 3) {
                    x += resid[off];
                } else if constexpr (EPI == 4) {
                    x *= 2.0f;
                }
                if constexpr (sizeof(OT) == 2) ((unsigned short*)out)[off] = f2b(x);
                else                           ((float*)out)[off] = x;
            }
        }
    }
}

// ---------------------------------------------------------------------------
// Fused MFMA fusion-attention (best measured config).
// grid (qt=4, b*h=48, i=4); block 256 = 4 waves; each wave owns 16 query rows.
// Swapped-operand scheme:
//   QK: mfma(kf, qf) -> S^T tile: lane = query (l15), regs = 4 contiguous keys.
//   PV: mfma(vf, pf) -> O^T tile: lane = query, regs = 4 contiguous d.
// LDS: KVu is Ks[128x64] during QK, Vt[64][136] during PV (union, 44032 B
// total -> 3 blocks/CU). V rows prefetched to regs one half ahead.
// ---------------------------------------------------------------------------
__launch_bounds__(256, 3)
__global__ void fusion_attn_mfma(const unsigned short* __restrict__ QKV,
                                 unsigned short* __restrict__ ctx)
{
    const int qt = blockIdx.x;
    const int b  = blockIdx.y / HEADS;
    const int h  = blockIdx.y % HEADS;
    const int i  = blockIdx.z;
    const int tid  = threadIdx.x;
    const int lane = tid & 63;
    const int wave = tid >> 6;
    const int l15  = lane & 15;
    const int quad = lane >> 4;

    __shared__ unsigned short Qs[64 * 72];     //  9216 B, wave-private rows
    __shared__ unsigned short KVu[64 * 136];   // 17408 B: Ks (QK) U Vt (PV)
    __shared__ unsigned short Ps[64 * 136];    // 17408 B

    {
        int r = tid >> 2, p16 = (tid & 3) * 16;
        const unsigned short* src = QKV + ((long)((i * 4 + b) * 256 + qt * 64 + r)) * 2304 + h * 64 + p16;
        *(ushort8*)(&Qs[r * 72 + p16])     = *(const ushort8*)(src);
        *(ushort8*)(&Qs[r * 72 + p16 + 8]) = *(const ushort8*)(src + 8);
    }

    const int kg = tid & 31;   // V prefetch: key group of 4 rows
    const int dc = tid >> 5;   // V prefetch: d-chunk (8 d-values)

    float4v acc_o[4];
    #pragma unroll
    for (int e = 0; e < 4; ++e) acc_o[e] = (float4v){0.f, 0.f, 0.f, 0.f};

    for (int j = 0; j < 4; ++j) {
        const unsigned short* Kb = QKV + ((long)((j * 4 + b) * 256)) * 2304 + 768 + h * 64;
        const unsigned short* Vb = Kb + 768;

        float4v sacc[16];
        #pragma unroll
        for (int t = 0; t < 16; ++t) sacc[t] = (float4v){0.f, 0.f, 0.f, 0.f};

        ushort8 vv0[4], vv1[4];

        // ---------------- QK half 0 ----------------
        __syncthreads();
        #pragma unroll
        for (int g = 0; g < 4; ++g) {
            int R = wave * 32 + g * 8;
            int r = R + (lane >> 3);
            int p = lane & 7;
            int c = (p - (r & 7)) & 7;
            const unsigned short* src = Kb + (long)(r) * 2304 + c * 8;
            __builtin_amdgcn_global_load_lds((gas_t*)src, (las_t*)&KVu[R * 64], 16, 0, 0);
        }
        __syncthreads();
        __builtin_amdgcn_s_setprio(1);
        #pragma unroll
        for (int ks = 0; ks < 2; ++ks) {
            int lcq = ks * 4 + quad;
            short8 qf = *(const short8*)&Qs[(wave * 16 + l15) * 72 + lcq * 8];
            #pragma unroll
            for (int nn = 0; nn < 8; ++nn) {
                int n = nn * 16 + l15;
                int p = (lcq + (n & 7)) & 7;
                short8 kf = *(const short8*)&KVu[n * 64 + p * 8];
                sacc[nn] = __builtin_amdgcn_mfma_f32_16x16x32_bf16(kf, qf, sacc[nn], 0, 0, 0);
            }
        }
        __builtin_amdgcn_s_setprio(0);

        // ---------------- QK half 1 ----------------
        __syncthreads();
        #pragma unroll
        for (int g = 0; g < 4; ++g) {
            int R = wave * 32 + g * 8;
            int r = R + (lane >> 3);
            int p = lane & 7;
            int c = (p - (r & 7)) & 7;
            const unsigned short* src = Kb + (long)(128 + r) * 2304 + c * 8;
            __builtin_amdgcn_global_load_lds((gas_t*)src, (las_t*)&KVu[R * 64], 16, 0, 0);
        }
        __builtin_amdgcn_sched_barrier(0);
        #pragma unroll
        for (int q = 0; q < 4; ++q)                // prefetch V half 0
            vv0[q] = *(const ushort8*)(Vb + (long)(kg * 4 + q) * 2304 + dc * 8);
        asm volatile("s_waitcnt vmcnt(4) lgkmcnt(0)" ::: "memory");
        __builtin_amdgcn_s_barrier();
        __builtin_amdgcn_sched_barrier(0);
        __builtin_amdgcn_s_setprio(1);
        #pragma unroll
        for (int ks = 0; ks < 2; ++ks) {
            int lcq = ks * 4 + quad;
            short8 qf = *(const short8*)&Qs[(wave * 16 + l15) * 72 + lcq * 8];
            #pragma unroll
            for (int nn = 0; nn < 8; ++nn) {
                int n = nn * 16 + l15;
                int p = (lcq + (n & 7)) & 7;
                short8 kf = *(const short8*)&KVu[n * 64 + p * 8];
                sacc[8 + nn] = __builtin_amdgcn_mfma_f32_16x16x32_bf16(kf, qf, sacc[8 + nn], 0, 0, 0);
            }
        }
        __builtin_amdgcn_s_setprio(0);

        // ---------------- softmax (register, per-query = per-lane) ----------
        float m = -1e30f;
        #pragma unroll
        for (int t = 0; t < 16; ++t)
            #pragma unroll
            for (int r = 0; r < 4; ++r) {
                sacc[t][r] *= 0.125f;
                m = fmaxf(m, sacc[t][r]);
            }
        m = fmaxf(m, __shfl_xor(m, 16));
        m = fmaxf(m, __shfl_xor(m, 32));
        float lsum = 0.f;
        #pragma unroll
        for (int t = 0; t < 16; ++t)
            #pragma unroll
            for (int r = 0; r < 4; ++r) {
                float e = __expf(sacc[t][r] - m);
                sacc[t][r] = e;
                lsum += e;
            }
        lsum += __shfl_xor(lsum, 16);
        lsum += __shfl_xor(lsum, 32);
        float invl = 1.0f / lsum;

        float4v pv[4];
        #pragma unroll
        for (int e = 0; e < 4; ++e) pv[e] = (float4v){0.f, 0.f, 0.f, 0.f};

        // ---------------- PV half 0 ----------------
        __syncthreads();
        #pragma unroll
        for (int nn = 0; nn < 8; ++nn) {
            unsigned lo = pack2b(sacc[nn][0], sacc[nn][1]);
            unsigned hi = pack2b(sacc[nn][2], sacc[nn][3]);
            *(unsigned long long*)&Ps[(wave * 16 + l15) * 136 + nn * 16 + quad * 4] =
                ((unsigned long long)hi << 32) | lo;
        }
        #pragma unroll
        for (int jj = 0; jj < 8; ++jj) {
            unsigned lo = (unsigned)vv0[0][jj] | ((unsigned)vv0[1][jj] << 16);
            unsigned hi = (unsigned)vv0[2][jj] | ((unsigned)vv0[3][jj] << 16);
            *(unsigned long long*)&KVu[(dc * 8 + jj) * 136 + kg * 4] =
                ((unsigned long long)hi << 32) | lo;
        }
        #pragma unroll
        for (int q = 0; q < 4; ++q)                // prefetch V half 1
            vv1[q] = *(const ushort8*)(Vb + (long)(128 + kg * 4 + q) * 2304 + dc * 8);
        asm volatile("s_waitcnt lgkmcnt(0)" ::: "memory");
        __builtin_amdgcn_s_barrier();
        __builtin_amdgcn_sched_barrier(0);
        __builtin_amdgcn_s_setprio(1);
        #pragma unroll
        for (int ks = 0; ks < 4; ++ks) {
            int lc = ks * 4 + quad;
            short8 pf = *(const short8*)&Ps[(wave * 16 + l15) * 136 + lc * 8];
            #pragma unroll
            for (int et = 0; et < 4; ++et) {
                short8 vf = *(const short8*)&KVu[(et * 16 + l15) * 136 + lc * 8];
                pv[et] = __builtin_amdgcn_mfma_f32_16x16x32_bf16(vf, pf, pv[et], 0, 0, 0);
            }
        }
        __builtin_amdgcn_s_setprio(0);

        // ---------------- PV half 1 ----------------
        __syncthreads();
        #pragma unroll
        for (int nn = 0; nn < 8; ++nn) {
            unsigned lo = pack2b(sacc[8 + nn][0], sacc[8 + nn][1]);
            unsigned hi = pack2b(sacc[8 + nn][2], sacc[8 + nn][3]);
            *(unsigned long long*)&Ps[(wave * 16 + l15) * 136 + nn * 16 + quad * 4] =
                ((unsigned long long)hi << 32) | lo;
        }
        #pragma unroll
        for (int jj = 0; jj < 8; ++jj) {
            unsigned lo = (unsigned)vv1[0][jj] | ((unsigned)vv1[1][jj] << 16);
            unsigned hi = (unsigned)vv1[2][jj] | ((unsigned)vv1[3][jj] << 16);
            *(unsigned long long*)&KVu[(dc * 8 + jj) * 136 + kg * 4] =
                ((unsigned long long)hi << 32) | lo;
        }
        __syncthreads();
        __builtin_amdgcn_s_setprio(1);
        #pragma unroll
        for (int ks = 0; ks < 4; ++ks) {
            int lc = ks * 4 + quad;
            short8 pf = *(const short8*)&Ps[(wave * 16 + l15) * 136 + lc * 8];
            #pragma unroll
            for (int et = 0; et < 4; ++et) {
                short8 vf = *(const short8*)&KVu[(et * 16 + l15) * 136 + lc * 8];
                pv[et] = __builtin_amdgcn_mfma_f32_16x16x32_bf16(vf, pf, pv[et], 0, 0, 0);
            }
        }
        __builtin_amdgcn_s_setprio(0);

        #pragma unroll
        for (int et = 0; et < 4; ++et)
            #pragma unroll
            for (int r = 0; r < 4; ++r)
                acc_o[et][r] += pv[et][r] * invl;
    }

    #pragma unroll
    for (int et = 0; et < 4; ++et) {
        unsigned lo = pack2b(acc_o[et][0] * 0.25f, acc_o[et][1] * 0.25f);
        unsigned hi = pack2b(acc_o[et][2] * 0.25f, acc_o[et][3] * 0.25f);
        long row = (long)((i * 4 + b) * 256 + qt * 64 + wave * 16 + l15);
        int  col = h * 64 + et * 16 + quad * 4;
        *(unsigned long long*)&ctx[row * 768 + col] = ((unsigned long long)hi << 32) | lo;
    }
}

// ---------------------------------------------------------------------------
// Learnable-query cross attention (f32). KVH [V,B,N,1536]: k then v.
// ---------------------------------------------------------------------------
__launch_bounds__(256, 2)
__global__ void cross_attn(const float* __restrict__ KVH, const float* __restrict__ QH,
                           float* __restrict__ C2)
{
    const int h = blockIdx.x, b = blockIdx.y, v = blockIdx.z;
    const int t = threadIdx.x;
    __shared__ float qv[64];
    __shared__ float p[256];
    __shared__ float part[4][64];
    __shared__ float wred[4], wred2[4];

    if (t < 64) qv[t] = QH[(v * 12 + h) * 64 + t];
    __syncthreads();

    const float* krow = KVH + ((long)((v * 4 + b) * 256 + t)) * 1536 + h * 64;
    float s = 0.f;
    #pragma unroll
    for (int e = 0; e < 64; e += 4) {
        float4 k4 = *(const float4*)(krow + e);
        s += qv[e] * k4.x + qv[e + 1] * k4.y + qv[e + 2] * k4.z + qv[e + 3] * k4.w;
    }
    s *= 0.125f;
    float m4 = s;
    #pragma unroll
    for (int off = 32; off > 0; off >>= 1) m4 = fmaxf(m4, __shfl_down(m4, off));
    if ((t & 63) == 0) wred[t >> 6] = m4;
    __syncthreads();
    float rmax = fmaxf(fmaxf(wred[0], wred[1]), fmaxf(wred[2], wred[3]));
    float ev = __expf(s - rmax);
    p[t] = ev;
    float s4 = ev;
    #pragma unroll
    for (int off = 32; off > 0; off >>= 1) s4 += __shfl_down(s4, off);
    if ((t & 63) == 0) wred2[t >> 6] = s4;
    __syncthreads();
    float inv = 1.0f / (wred2[0] + wred2[1] + wred2[2] + wred2[3]);

    const int e = t & 63, ch = t >> 6;
    const float* vbase = KVH + ((long)((v * 4 + b) * 256)) * 1536 + 768 + h * 64 + e;
    float accv = 0.f;
    for (int m = ch * 64; m < ch * 64 + 64; ++m)
        accv += p[m] * vbase[(long)m * 1536];
    part[ch][e] = accv;
    __syncthreads();
    if (t < 64)
        C2[(v * 4 + b) * 768 + h * 64 + t] =
            (part[0][t] + part[1][t] + part[2][t] + part[3][t]) * inv;
}

// ---------------------------------------------------------------------------
// out stage 1: one wave per output row d; 768 blocks x 4 waves.
// ---------------------------------------------------------------------------
__launch_bounds__(256, 4)
__global__ void out_matvec(const float* __restrict__ C2, const float* __restrict__ Wout,
                           const float* __restrict__ Bout, float* __restrict__ obc)
{
    const int bi   = blockIdx.x;
    const int v    = bi / 192;
    const int dblk = bi - v * 192;
    const int t    = threadIdx.x;
    const int wave = t >> 6;
    const int lane = t & 63;
    const int d    = dblk * 4 + wave;

    __shared__ float c2s[3072];
    #pragma unroll
    for (int idx = 0; idx < 3072; idx += 256) c2s[idx + t] = C2[v * 3072 + idx + t];
    __syncthreads();

    const float* w = Wout + ((long)v * 768 + d) * 768;
    float acc0 = 0.f, acc1 = 0.f, acc2 = 0.f, acc3 = 0.f;
    #pragma unroll
    for (int k = 0; k < 3; ++k) {
        int c = k * 256 + lane * 4;
        float4 w4 = *(const float4*)(w + c);
        float4 a0 = *(const float4*)&c2s[c];
        float4 a1 = *(const float4*)&c2s[768 + c];
        float4 a2 = *(const float4*)&c2s[1536 + c];
        float4 a3 = *(const float4*)&c2s[2304 + c];
        acc0 += w4.x * a0.x + w4.y * a0.y + w4.z * a0.z + w4.w * a0.w;
        acc1 += w4.x * a1.x + w4.y * a1.y + w4.z * a1.z + w4.w * a1.w;
        acc2 += w4.x * a2.x + w4.y * a2.y + w4.z * a2.z + w4.w * a2.w;
        acc3 += w4.x * a3.x + w4.y * a3.y + w4.z * a3.z + w4.w * a3.w;
    }
    #pragma unroll
    for (int off = 32; off > 0; off >>= 1) {
        acc0 += __shfl_down(acc0, off);
        acc1 += __shfl_down(acc1, off);
        acc2 += __shfl_down(acc2, off);
        acc3 += __shfl_down(acc3, off);
    }
    if (lane == 0) {
        float bb = Bout[v * 768 + d];
        obc[0 * 3072 + v * 768 + d] = acc0 + bb;
        obc[1 * 3072 + v * 768 + d] = acc1 + bb;
        obc[2 * 3072 + v * 768 + d] = acc2 + bb;
        obc[3 * 3072 + v * 768 + d] = acc3 + bb;
    }
}

// ---------------------------------------------------------------------------
// out stage 2: broadcast over N
// ---------------------------------------------------------------------------
__launch_bounds__(256, 4)
__global__ void out_bcast(const float* __restrict__ obc, float* __restrict__ out)
{
    const int b  = blockIdx.x >> 6;
    const int n0 = (blockIdx.x & 63) * 4;
    const int t  = threadIdx.x;
    const float4* src = (const float4*)(obc + (long)b * 3072);
    float4 v0 = src[t], v1 = src[t + 256], v2 = src[t + 512];
    float4* dst = (float4*)(out + ((long)(b * 256 + n0)) * 3072);
    #pragma unroll
    for (int r = 0; r < 4; ++r) {
        dst[r * 768 + t]       = v0;
        dst[r * 768 + t + 256] = v1;
        dst[r * 768 + t + 512] = v2;
    }
}

// ---------------------------------------------------------------------------
extern "C" void kernel_launch(void* const* d_in, const int* in_sizes, int n_in,
                              void* d_out, int out_size, void* d_ws, size_t ws_size,
                              hipStream_t stream)
{
    const float* X        = (const float*)d_in[0];
    const float* n1g      = (const float*)d_in[1];
    const float* n1b      = (const float*)d_in[2];
    const float* qkv_w    = (const float*)d_in[3];
    const float* proj_w   = (const float*)d_in[4];
    const float* proj_b   = (const float*)d_in[5];
    const float* n2g      = (const float*)d_in[6];
    const float* n2b      = (const float*)d_in[7];
    const float* fc1_w    = (const float*)d_in[8];
    const float* fc1_b    = (const float*)d_in[9];
    const float* fc2_w    = (const float*)d_in[10];
    const float* fc2_b    = (const float*)d_in[11];
    const float* query    = (const float*)d_in[12];
    const float* mha_in_w = (const float*)d_in[13];
    const float* mha_in_b = (const float*)d_in[14];
    const float* mha_out_w= (const float*)d_in[15];
    const float* mha_out_b= (const float*)d_in[16];
    float* out = (float*)d_out;

    // ws is 256 MiB -> all bf16 weights coexist. Element offsets in wbuf:
    //   qkv 0 | proj 7077888 | fc1 9437184 | fc2 18874368 | mha_in 28311552
    char* wsb = (char*)d_ws;
    unsigned short* wbuf = (unsigned short*)wsb;                    // 70,778,880 B
    unsigned short* rgA  = (unsigned short*)(wsb + 70778880);       //  6,291,456 B (Xn -> ctx -> h -> x2)
    char*           rgB  = wsb + 77070336;                          // 25,165,824 B (QKV -> h1 -> KVH)
    float*          xbuf = (float*)(wsb + 102236160);               // 12,582,912 B (x residual, f32)
    float*          qh   = (float*)(wsb + 114819072);               // 12,288 B
    float*          c2   = (float*)(wsb + 114831360);               // 49,152 B
    float*          obc  = (float*)(wsb + 114880512);               // 49,152 B

    unsigned short* QKV = (unsigned short*)rgB;
    unsigned short* H1  = (unsigned short*)rgB;
    float*          KVH = (float*)rgB;

    // 1. fused prologue: conv (4096, long-pole-first) + LN1 (4096) + qh (768)
    prologue<<<8960, 256, 0, stream>>>(X, n1g, n1b, rgA,
                                       query, mha_in_w, mha_in_b, qh,
                                       qkv_w, proj_w, fc1_w, fc2_w, mha_in_w, wbuf);
    // 2. QKV = Xn @ qkv_w^T  [V,1024,2304] bf16   (TM=128/BK=64; 576 blocks)
    gemm_bf16<0, 128, 64, unsigned short><<<dim3(18, 8, 4), 256, 0, stream>>>(
        rgA, wbuf, nullptr, nullptr, QKV, 1024, 2304, 768, 2304L * 768, 0, 0, 0);
    // 3. fusion attention -> ctx_mean bf16 [V,1024,768]
    fusion_attn_mfma<<<dim3(4, 48, 4), 256, 0, stream>>>(QKV, rgA);
    // 4. x = 2*(ctx @ proj_w^T + proj_b)  f32    (TM=64/BK=128; 384 blocks)
    gemm_bf16<4, 64, 128, float><<<dim3(6, 16, 4), 256, 0, stream>>>(
        rgA, wbuf + 7077888, proj_b, nullptr, xbuf, 1024, 768, 768, 768L * 768, 0, 768, 0);
    // 5. h = LN2(x) bf16
    ln2_kernel<<<4096, 256, 0, stream>>>(xbuf, n2g, n2b, rgA);
    // 6. h1 = gelu(h @ fc1_w^T + fc1_b) bf16 [V,1024,3072]  (TM=128/BK=64; 768 blocks)
    gemm_bf16<2, 128, 64, unsigned short><<<dim3(24, 8, 4), 256, 0, stream>>>(
        rgA, wbuf + 9437184, fc1_b, nullptr, H1, 1024, 3072, 768, 3072L * 768, 0, 3072, 0);
    // 7. x2 = x + (h1 @ fc2_w^T + fc2_b) bf16   (TM=64/BK=128; 384 blocks)
    gemm_bf16<3, 64, 128, unsigned short><<<dim3(6, 16, 4), 256, 0, stream>>>(
        H1, wbuf + 18874368, fc2_b, xbuf, rgA, 1024, 768, 3072, 768L * 3072, 0, 768, 0);
    // 8. KVH = x2 @ [wk;wv]^T + [bk;bv]  f32 [V,1024,1536]  (TM=64/BK=128; 768 blocks)
    gemm_bf16<1, 64, 128, float><<<dim3(12, 16, 4), 256, 0, stream>>>(
        rgA, wbuf + 28311552, mha_in_b, nullptr, KVH, 1024, 1536, 768, 2304L * 768, 768L * 768, 2304, 768);
    // 9. small tail
    cross_attn<<<dim3(12, 4, 4), 256, 0, stream>>>(KVH, qh, c2);
    out_matvec<<<768, 256, 0, stream>>>(c2, mha_out_w, mha_out_b, obc);
    out_bcast<<<256, 256, 0, stream>>>(obc, out);
}